// Round 7
// baseline (135.202 us; speedup 1.0000x reference)
//
#include <hip/hip_runtime.h>
#include <hip/hip_bf16.h>
#include <hip/hip_cooperative_groups.h>

namespace cg = cooperative_groups;

// Problem constants (match reference)
constexpr int BB = 16384;   // batch
constexpr int CC = 2048;    // classes
constexpr int DD = 256;     // dim
constexpr float THR   = 0.8f;
constexpr float EPSN  = 1e-8f;

typedef __bf16 bf16x8 __attribute__((ext_vector_type(8)));
typedef float  f32x4  __attribute__((ext_vector_type(4)));

// ---------------- workspace layout (bytes) ----------------
// [0)         cls    : B*4   = 65,536   (fully rewritten every call)
// [65,536)    exists : C*4   = 8,192    (fully rewritten every call)
// [73,728)    pn     : B*D*2 = 8,388,608 (bf16, fully rewritten)
// [8,462,336) cn     : C*D*2 = 1,048,576 (bf16, fully rewritten)
// No memsets needed: every byte above is unconditionally written each call.
constexpr int SLOTS = 48;   // max rows/class tracked; P(Binom(16384,1/2048)>48) ~ 0

// Kernel A: blocks [0,2048) stream labels -> cls[row] (one-hot: exactly one
// writer per row, no atomics); blocks [2048,6144) normalize preds -> pn bf16.
// Also zeroes the output scalar (block 0).
__global__ __launch_bounds__(256) void k_scan_pn(const float* __restrict__ labels,
                                                 const float* __restrict__ preds,
                                                 int* __restrict__ cls,
                                                 unsigned short* __restrict__ pn,
                                                 float* __restrict__ out) {
  if (blockIdx.x < 2048) {
    if (blockIdx.x == 0 && threadIdx.x == 0) *out = 0.f;
    constexpr size_t total = (size_t)BB * CC / 4;
    size_t q = (size_t)blockIdx.x * 256 + threadIdx.x;
    const float4* l4 = reinterpret_cast<const float4*>(labels);
    for (; q < total; q += 2048 * 256) {
      float4 v = l4[q];
      if (v.x >= THR || v.y >= THR || v.z >= THR || v.w >= THR) {
        int f = (int)(q * 4);
        int row = f >> 11;      // / CC
        int col = f & (CC - 1);
        cls[row] = col + (v.x >= THR ? 0 : v.y >= THR ? 1 : v.z >= THR ? 2 : 3);
      }
    }
  } else {
    int b = (blockIdx.x - 2048) * 4 + (threadIdx.x >> 6);
    int lane = threadIdx.x & 63;
    float4 v = reinterpret_cast<const float4*>(preds + (size_t)b * DD)[lane];
    float s = v.x * v.x + v.y * v.y + v.z * v.z + v.w * v.w;
#pragma unroll
    for (int o = 32; o > 0; o >>= 1) s += __shfl_xor(s, o);
    float inv = 1.0f / fmaxf(sqrtf(s), EPSN);
    union { ushort4 u4; unsigned short us[4]; } o;
    float f0 = v.x * inv, f1 = v.y * inv, f2 = v.z * inv, f3 = v.w * inv;
    __bf16 h0 = (__bf16)f0, h1 = (__bf16)f1, h2 = (__bf16)f2, h3 = (__bf16)f3;
    o.us[0] = *reinterpret_cast<unsigned short*>(&h0);
    o.us[1] = *reinterpret_cast<unsigned short*>(&h1);
    o.us[2] = *reinterpret_cast<unsigned short*>(&h2);
    o.us[3] = *reinterpret_cast<unsigned short*>(&h3);
    reinterpret_cast<ushort4*>(pn + (size_t)b * DD)[lane] = o.u4;
  }
}

// ---- Kernel B (cooperative, 256 blocks x 512 thr, 1 block/CU via 128KB LDS):
// phase 0: per-block 8 classes: cls scan -> LDS rowlists -> centroid mean ->
//          normalize -> cn bf16 + exists.
// grid.sync()
// phase 1: E = sum(exists); GEMM 2 tiles/block (r4 structure, verified) +
//          fused epilogue -> atomicAdd(out).
// GEMM swizzle (rule #21, both-sides, conflict-free r2-r6): element (row,kb)
// at byte row*128 + (kb ^ ((row&7)<<4)); gload_lds dest linear, SOURCE
// inverse-permuted, ds_read same XOR.

__device__ __forceinline__ void stage32k(char* lds, const char* gsrc_row0,
                                         int tid, int ksbyte) {
#pragma unroll
  for (int i = 0; i < 4; ++i) {
    int L = i * 8192 + tid * 16;             // linear LDS byte (32KB / 512thr)
    int row = L >> 7;                        // 128B per row (64 k * 2B)
    int kb  = (L & 127) ^ ((row & 7) << 4);  // involution
    const char* g = gsrc_row0 + (size_t)row * (DD * 2) + ksbyte + kb;
    __builtin_amdgcn_global_load_lds(
        (const __attribute__((address_space(1))) unsigned int*)g,
        (__attribute__((address_space(3))) unsigned int*)(lds + L), 16, 0, 0);
  }
}

__device__ __forceinline__ bf16x8 ldfrag(const char* buf, int row, int kb) {
  return *reinterpret_cast<const bf16x8*>(buf + row * 128 + (kb ^ ((row & 7) << 4)));
}

__global__ __launch_bounds__(512, 2) void k_main(
    const float* __restrict__ preds, const unsigned short* __restrict__ pn,
    const int* __restrict__ cls, unsigned short* __restrict__ cn,
    int* __restrict__ exists, float* __restrict__ out) {
  constexpr int BM = 256, BN = 256;
  __shared__ __align__(16) char sA[2][BM * 64 * 2];   // 2 x 32KB
  __shared__ __align__(16) char sB[2][BN * 64 * 2];   // 2 x 32KB
  __shared__ int   s_cnt[8];
  __shared__ int   s_rows[8][SLOTS];
  __shared__ float s_red[2][4];
  __shared__ float red[8];

  int bid = blockIdx.x;
  int tid = threadIdx.x;

  // ---------------- phase 0: centroids for classes [bid*8, bid*8+8) --------
  if (tid < 8) s_cnt[tid] = 0;
  __syncthreads();
  int c0 = bid * 8;
  for (int i = tid; i < BB; i += 512) {
    int c = cls[i];
    if ((c >> 3) == bid) {
      int slot = atomicAdd(&s_cnt[c & 7], 1);
      if (slot < SLOTS) s_rows[c & 7][slot] = i;
    }
  }
  __syncthreads();
  {
    int sub = tid >> 8, dim = tid & 255;    // two 256-thread groups
    for (int g = 0; g < 4; ++g) {
      int lc = g * 2 + sub;                 // local class 0..7
      int c = c0 + lc;
      int n = s_cnt[lc];
      int nn = n < SLOTS ? n : SLOTS;
      float sum = 0.f;
      for (int i = 0; i < nn; ++i)
        sum += preds[(size_t)s_rows[lc][i] * DD + dim];
      float mean = sum / (float)(n > 0 ? n : 1);
      float ss = mean * mean;
#pragma unroll
      for (int o = 32; o > 0; o >>= 1) ss += __shfl_xor(ss, o);
      int wv = (tid >> 6) & 3;
      if ((tid & 63) == 0) s_red[sub][wv] = ss;
      __syncthreads();
      float tot = s_red[sub][0] + s_red[sub][1] + s_red[sub][2] + s_red[sub][3];
      float inv = 1.0f / fmaxf(sqrtf(tot), EPSN);
      __bf16 h = (__bf16)(mean * inv);
      cn[(size_t)c * DD + dim] = *reinterpret_cast<unsigned short*>(&h);
      if (dim == 0) exists[c] = (n > 0) ? 1 : 0;
      __syncthreads();                      // s_red reuse next g
    }
  }

  // ---------------- grid-wide barrier (device-scope fences included) -------
  cg::this_grid().sync();

  // ---------------- phase 1: E = #existing centroids -----------------------
  int w = tid >> 6, lane = tid & 63;
  float ee = 0.f;
  for (int i = tid; i < CC; i += 512) ee += (float)exists[i];
#pragma unroll
  for (int o = 32; o > 0; o >>= 1) ee += __shfl_xor(ee, o);
  if (lane == 0) red[w] = ee;
  __syncthreads();
  int E = (int)(red[0] + red[1] + red[2] + red[3] +
                red[4] + red[5] + red[6] + red[7]);
  float inv_B = 1.0f / (float)BB;
  float inv_neg = inv_B / (float)((E - 1) > 0 ? (E - 1) : 1);
  __syncthreads();                          // red reused by epilogue

  // ---------------- phase 2: GEMM, 2 tiles per block -----------------------
  int wm = w >> 2, wn = w & 3;              // wave grid 2 x 4
  int r16 = lane & 15, khi = lane >> 4;     // khi in 0..3
  int arow0 = wm * 128 + r16;
  int brow0 = wn * 64 + r16;
  int ntile = bid & 7;                      // 8 ntiles ~ 8 XCDs (cn L2-local)
  int colbase = ntile * BN;
  const char* cnB = (const char*)cn + (size_t)colbase * (DD * 2);

  for (int tt = 0; tt < 2; ++tt) {
    int mtile = (bid >> 3) * 2 + tt;        // 32 mgroups x 2 = 64 mtiles
    int rowbase = mtile * BM;
    const char* pnB = (const char*)pn + (size_t)rowbase * (DD * 2);

    f32x4 acc[8][4];
#pragma unroll
    for (int m = 0; m < 8; ++m)
#pragma unroll
      for (int n = 0; n < 4; ++n) acc[m][n] = {0.f, 0.f, 0.f, 0.f};

    stage32k(sA[0], pnB, tid, 0);
    stage32k(sB[0], cnB, tid, 0);
    __syncthreads();

    int cur = 0;
#pragma unroll
    for (int ks = 0; ks < 4; ++ks) {        // 256 / BK = 4 K-steps
      if (ks < 3) {
        stage32k(sA[cur ^ 1], pnB, tid, (ks + 1) * 128);
        stage32k(sB[cur ^ 1], cnB, tid, (ks + 1) * 128);
      }
      const char* bufA = sA[cur];
      const char* bufB = sB[cur];
#pragma unroll
      for (int kk = 0; kk < 2; ++kk) {      // 2 x K=32 per BK=64
        int kb = kk * 64 + khi * 16;
        bf16x8 b[4];
#pragma unroll
        for (int n = 0; n < 4; ++n) b[n] = ldfrag(bufB, brow0 + n * 16, kb);
#pragma unroll
        for (int m = 0; m < 8; ++m) {
          bf16x8 a = ldfrag(bufA, arow0 + m * 16, kb);
#pragma unroll
          for (int n = 0; n < 4; ++n)
            acc[m][n] = __builtin_amdgcn_mfma_f32_16x16x32_bf16(a, b[n], acc[m][n], 0, 0, 0);
        }
      }
      __syncthreads();                      // staged loads landed + reads done
      cur ^= 1;
    }

    // Epilogue (verified r1-r6): pos (diagonal) + hinge neg -> scalar atomic.
    // D layout: col = lane&15, row = (lane>>4)*4 + reg  (m89-verified)
    int grow0 = rowbase + wm * 128;
    int clsr[8][4];
#pragma unroll
    for (int m = 0; m < 8; ++m)
#pragma unroll
      for (int r = 0; r < 4; ++r) clsr[m][r] = cls[grow0 + m * 16 + khi * 4 + r];
    int exs[4];
#pragma unroll
    for (int n = 0; n < 4; ++n) exs[n] = exists[colbase + wn * 64 + n * 16 + r16];

    float local = 0.f;
#pragma unroll
    for (int m = 0; m < 8; ++m)
#pragma unroll
      for (int n = 0; n < 4; ++n) {
        int ccol = colbase + wn * 64 + n * 16 + r16;
#pragma unroll
        for (int r = 0; r < 4; ++r) {
          float v = acc[m][n][r];
          if (ccol == clsr[m][r])
            local += (1.0f - v) * inv_B;              // pos: 1 - cos
          else if (exs[n])
            local += fmaxf(v - 0.7f, 0.f) * inv_neg;  // relu(M_NEG-(1-cos))
        }
      }

#pragma unroll
    for (int o = 32; o > 0; o >>= 1) local += __shfl_xor(local, o);
    if (lane == 0) red[w] = local;
    __syncthreads();
    if (tid == 0) {
      float t = 0.f;
#pragma unroll
      for (int i = 0; i < 8; ++i) t += red[i];
      atomicAdd(out, t);
    }
  }
}

extern "C" void kernel_launch(void* const* d_in, const int* in_sizes, int n_in,
                              void* d_out, int out_size, void* d_ws, size_t ws_size,
                              hipStream_t stream) {
  const float* preds  = (const float*)d_in[0];
  const float* labels = (const float*)d_in[1];
  float* out = (float*)d_out;

  char* ws = (char*)d_ws;
  int*            cls    = (int*)(ws + 0);
  int*            exists = (int*)(ws + 65536);
  unsigned short* pn     = (unsigned short*)(ws + 73728);
  unsigned short* cn     = (unsigned short*)(ws + 8462336);

  k_scan_pn<<<6144, 256, 0, stream>>>(labels, preds, cls, pn, out);

  const float* preds_a = preds;
  const unsigned short* pn_a = pn;
  const int* cls_a = cls;
  unsigned short* cn_a = cn;
  int* exists_a = exists;
  float* out_a = out;
  void* args[] = {&preds_a, &pn_a, &cls_a, &cn_a, &exists_a, &out_a};
  hipLaunchCooperativeKernel(reinterpret_cast<void*>(k_main),
                             dim3(256), dim3(512), args, 0, stream);
}

// Round 8
// 107.390 us; speedup vs baseline: 1.2590x; 1.2590x over previous
//
#include <hip/hip_runtime.h>
#include <hip/hip_bf16.h>

// Problem constants (match reference)
constexpr int BB = 16384;   // batch
constexpr int CC = 2048;    // classes
constexpr int DD = 256;     // dim
constexpr float THR   = 0.8f;
constexpr float EPSN  = 1e-8f;

typedef __bf16 bf16x8 __attribute__((ext_vector_type(8)));
typedef float  f32x4  __attribute__((ext_vector_type(4)));

// ---------------- workspace layout (bytes) ----------------
// [0)         cls    : B*4   = 65,536    (fully rewritten every call)
// [65,536)    exists : C*4   = 8,192     (fully rewritten every call)
// [73,728)    Ecnt   : 4 (pad to 73,792) (zeroed by k_scan_pn, pre-k_cn)
// [73,792)    pn     : B*D*2 = 8,388,608 (bf16, fully rewritten)
// [8,462,400) cn     : C*D*2 = 1,048,576 (bf16, fully rewritten)
// No memset nodes: every byte is written each call (Ecnt/out zeroed by K1).
constexpr int SLOTS = 48;   // max rows/class; P(Binom(16384,1/2048) > 48) ~ 1e-30

// K1: blocks [0,2048) stream labels -> cls[row] (one-hot: exactly one writer
// per row, no atomics) + zero out/Ecnt; blocks [2048,6144) normalize preds
// -> pn bf16 (one wave per row). ~150MB @ HBM floor.
__global__ __launch_bounds__(256) void k_scan_pn(const float* __restrict__ labels,
                                                 const float* __restrict__ preds,
                                                 int* __restrict__ cls,
                                                 unsigned short* __restrict__ pn,
                                                 int* __restrict__ Ecnt,
                                                 float* __restrict__ out) {
  if (blockIdx.x < 2048) {
    if (blockIdx.x == 0 && threadIdx.x == 0) { *out = 0.f; *Ecnt = 0; }
    constexpr size_t total = (size_t)BB * CC / 4;
    size_t q = (size_t)blockIdx.x * 256 + threadIdx.x;
    const float4* l4 = reinterpret_cast<const float4*>(labels);
    for (; q < total; q += 2048 * 256) {
      float4 v = l4[q];
      if (v.x >= THR || v.y >= THR || v.z >= THR || v.w >= THR) {
        int f = (int)(q * 4);
        int row = f >> 11;      // / CC
        int col = f & (CC - 1);
        cls[row] = col + (v.x >= THR ? 0 : v.y >= THR ? 1 : v.z >= THR ? 2 : 3);
      }
    }
  } else {
    int b = (blockIdx.x - 2048) * 4 + (threadIdx.x >> 6);
    int lane = threadIdx.x & 63;
    float4 v = reinterpret_cast<const float4*>(preds + (size_t)b * DD)[lane];
    float s = v.x * v.x + v.y * v.y + v.z * v.z + v.w * v.w;
#pragma unroll
    for (int o = 32; o > 0; o >>= 1) s += __shfl_xor(s, o);
    float inv = 1.0f / fmaxf(sqrtf(s), EPSN);
    union { ushort4 u4; unsigned short us[4]; } o;
    float f0 = v.x * inv, f1 = v.y * inv, f2 = v.z * inv, f3 = v.w * inv;
    __bf16 h0 = (__bf16)f0, h1 = (__bf16)f1, h2 = (__bf16)f2, h3 = (__bf16)f3;
    o.us[0] = *reinterpret_cast<unsigned short*>(&h0);
    o.us[1] = *reinterpret_cast<unsigned short*>(&h1);
    o.us[2] = *reinterpret_cast<unsigned short*>(&h2);
    o.us[3] = *reinterpret_cast<unsigned short*>(&h3);
    reinterpret_cast<ushort4*>(pn + (size_t)b * DD)[lane] = o.u4;
  }
}

// K2: one block per class. Scan cls (64KB, L2-hot after first touch) to find
// this class's rows (LDS list, no global rowlist/memset), gather ~8 preds
// rows, mean, normalize -> cn bf16 + exists + Ecnt.
__global__ __launch_bounds__(256) void k_cn(const float* __restrict__ preds,
                                            const int* __restrict__ cls,
                                            unsigned short* __restrict__ cn,
                                            int* __restrict__ exists,
                                            int* __restrict__ Ecnt) {
  int c = blockIdx.x;
  int t = threadIdx.x;
  __shared__ int s_cnt;
  __shared__ int s_rows[SLOTS];
  __shared__ float red[4];
  if (t == 0) s_cnt = 0;
  __syncthreads();
  for (int i = t; i < BB; i += 256) {
    if (cls[i] == c) {
      int slot = atomicAdd(&s_cnt, 1);
      if (slot < SLOTS) s_rows[slot] = i;
    }
  }
  __syncthreads();
  int n = s_cnt;
  int nn = n < SLOTS ? n : SLOTS;
  float sum = 0.f;
  for (int i = 0; i < nn; ++i)
    sum += preds[(size_t)s_rows[i] * DD + t];
  float mean = sum / (float)(n > 0 ? n : 1);
  float ss = mean * mean;
#pragma unroll
  for (int o = 32; o > 0; o >>= 1) ss += __shfl_xor(ss, o);
  int wave = t >> 6, lane = t & 63;
  if (lane == 0) red[wave] = ss;
  __syncthreads();
  float tot = red[0] + red[1] + red[2] + red[3];
  float inv = 1.0f / fmaxf(sqrtf(tot), EPSN);
  __bf16 h = (__bf16)(mean * inv);
  cn[(size_t)c * DD + t] = *reinterpret_cast<unsigned short*>(&h);
  if (t == 0) {
    exists[c] = (n > 0) ? 1 : 0;
    if (n > 0) atomicAdd(Ecnt, 1);
  }
}

// K3: r4-exact GEMM (measured ~12us in r6): 256x256 tile, BK=64, 8 waves,
// dbuf 128KB LDS, one __syncthreads per K-step, fused epilogue -> atomic.
// Swizzle (rule #21, both-sides, conflict-free r2-r7): element (row,kb) at
// byte row*128 + (kb ^ ((row&7)<<4)); gload_lds dest linear, SOURCE
// inverse-permuted, ds_read same XOR.

__device__ __forceinline__ void stage32k(char* lds, const char* gsrc_row0,
                                         int tid, int ksbyte) {
#pragma unroll
  for (int i = 0; i < 4; ++i) {
    int L = i * 8192 + tid * 16;             // linear LDS byte (32KB / 512thr)
    int row = L >> 7;                        // 128B per row (64 k * 2B)
    int kb  = (L & 127) ^ ((row & 7) << 4);  // involution
    const char* g = gsrc_row0 + (size_t)row * (DD * 2) + ksbyte + kb;
    __builtin_amdgcn_global_load_lds(
        (const __attribute__((address_space(1))) unsigned int*)g,
        (__attribute__((address_space(3))) unsigned int*)(lds + L), 16, 0, 0);
  }
}

__device__ __forceinline__ bf16x8 ldfrag(const char* buf, int row, int kb) {
  return *reinterpret_cast<const bf16x8*>(buf + row * 128 + (kb ^ ((row & 7) << 4)));
}

__global__ __launch_bounds__(512, 2) void k_loss(
    const unsigned short* __restrict__ pn, const unsigned short* __restrict__ cn,
    const int* __restrict__ cls, const int* __restrict__ exists,
    const int* __restrict__ Ecnt, float* __restrict__ out) {
  constexpr int BM = 256, BN = 256;
  __shared__ __align__(16) char sA[2][BM * 64 * 2];   // 2 x 32KB
  __shared__ __align__(16) char sB[2][BN * 64 * 2];   // 2 x 32KB
  __shared__ float red[8];

  // 512 blocks = 64 mtiles x 8 ntiles; bijective XCD swizzle (512 % 8 == 0).
  int bid = blockIdx.x;
  int nb = (bid & 7) * 64 + (bid >> 3);
  int mtile = nb & 63;
  int ntile = nb >> 6;
  int rowbase = mtile * BM, colbase = ntile * BN;
  int tid = threadIdx.x, w = tid >> 6, lane = tid & 63;
  int wm = w >> 2, wn = w & 3;            // wave grid 2 x 4
  int r16 = lane & 15, khi = lane >> 4;   // khi in 0..3
  int arow0 = wm * 128 + r16;             // LDS-A row base for a-frags
  int brow0 = wn * 64 + r16;              // LDS-B row base for b-frags

  const char* pnB = (const char*)pn + (size_t)rowbase * (DD * 2);
  const char* cnB = (const char*)cn + (size_t)colbase * (DD * 2);

  f32x4 acc[8][4];
#pragma unroll
  for (int m = 0; m < 8; ++m)
#pragma unroll
    for (int n = 0; n < 4; ++n) acc[m][n] = {0.f, 0.f, 0.f, 0.f};

  stage32k(sA[0], pnB, tid, 0);
  stage32k(sB[0], cnB, tid, 0);
  __syncthreads();

  int cur = 0;
#pragma unroll
  for (int ks = 0; ks < 4; ++ks) {        // 256 / BK = 4 K-steps
    if (ks < 3) {                         // issue next stage BEFORE compute
      stage32k(sA[cur ^ 1], pnB, tid, (ks + 1) * 128);
      stage32k(sB[cur ^ 1], cnB, tid, (ks + 1) * 128);
    }
    const char* bufA = sA[cur];
    const char* bufB = sB[cur];
#pragma unroll
    for (int kk = 0; kk < 2; ++kk) {      // 2 x K=32 per BK=64
      int kb = kk * 64 + khi * 16;
      bf16x8 b[4];
#pragma unroll
      for (int n = 0; n < 4; ++n) b[n] = ldfrag(bufB, brow0 + n * 16, kb);
#pragma unroll
      for (int m = 0; m < 8; ++m) {
        bf16x8 a = ldfrag(bufA, arow0 + m * 16, kb);
#pragma unroll
        for (int n = 0; n < 4; ++n)
          acc[m][n] = __builtin_amdgcn_mfma_f32_16x16x32_bf16(a, b[n], acc[m][n], 0, 0, 0);
      }
    }
    __syncthreads();                      // staged loads landed + reads done
    cur ^= 1;
  }

  // Epilogue (verified r1-r7): pos (diagonal) + hinge neg -> scalar atomic.
  // D layout: col = lane&15, row = (lane>>4)*4 + reg  (m89-verified)
  int E = *Ecnt;
  float inv_B = 1.0f / (float)BB;
  float inv_neg = inv_B / (float)((E - 1) > 0 ? (E - 1) : 1);
  int grow0 = rowbase + wm * 128;

  int clsr[8][4];
#pragma unroll
  for (int m = 0; m < 8; ++m)
#pragma unroll
    for (int r = 0; r < 4; ++r) clsr[m][r] = cls[grow0 + m * 16 + khi * 4 + r];
  int exs[4];
#pragma unroll
  for (int n = 0; n < 4; ++n) exs[n] = exists[colbase + wn * 64 + n * 16 + r16];

  float local = 0.f;
#pragma unroll
  for (int m = 0; m < 8; ++m)
#pragma unroll
    for (int n = 0; n < 4; ++n) {
      int ccol = colbase + wn * 64 + n * 16 + r16;
#pragma unroll
      for (int r = 0; r < 4; ++r) {
        float v = acc[m][n][r];
        if (ccol == clsr[m][r])
          local += (1.0f - v) * inv_B;              // pos: 1 - cos(b, cls[b])
        else if (exs[n])
          local += fmaxf(v - 0.7f, 0.f) * inv_neg;  // relu(M_NEG - (1 - cos))
      }
    }

#pragma unroll
  for (int o = 32; o > 0; o >>= 1) local += __shfl_xor(local, o);
  if (lane == 0) red[w] = local;
  __syncthreads();
  if (tid == 0) {
    float t = 0.f;
#pragma unroll
    for (int i = 0; i < 8; ++i) t += red[i];
    atomicAdd(out, t);
  }
}

extern "C" void kernel_launch(void* const* d_in, const int* in_sizes, int n_in,
                              void* d_out, int out_size, void* d_ws, size_t ws_size,
                              hipStream_t stream) {
  const float* preds  = (const float*)d_in[0];
  const float* labels = (const float*)d_in[1];
  float* out = (float*)d_out;

  char* ws = (char*)d_ws;
  int*            cls    = (int*)(ws + 0);
  int*            exists = (int*)(ws + 65536);
  int*            Ecnt   = (int*)(ws + 73728);
  unsigned short* pn     = (unsigned short*)(ws + 73792);
  unsigned short* cn     = (unsigned short*)(ws + 8462400);

  k_scan_pn<<<6144, 256, 0, stream>>>(labels, preds, cls, pn, Ecnt, out);
  k_cn<<<CC, 256, 0, stream>>>(preds, cls, cn, exists, Ecnt);
  k_loss<<<512, 512, 0, stream>>>(pn, cn, cls, exists, Ecnt, out);
}